// Round 9
// baseline (414.988 us; speedup 1.0000x reference)
//
#include <hip/hip_runtime.h>
#include <hip/hip_bf16.h>
#include <math.h>

#define NIMG 1024
#define NPATCH 64
#define PDIM 192
#define KCODES 4096
#define EDIM 2048
#define VDIM 2048
#define MROWS (NIMG * NPATCH)   // 65536
#define KP 384                  // storage: [0,192)=hi, [192,384)=lo
#define NKS 18                  // K-steps (BK=32) per column tile: virtual K=576
#define NCT 16                  // column tiles of 256 codes
#define NKT (NCT * NKS)         // 288 flat K-steps

typedef __attribute__((ext_vector_type(8))) short bf16x8;
typedef __attribute__((ext_vector_type(16))) float f32x16;

__device__ __forceinline__ void gload_lds16(const void* g, void* l) {
    __builtin_amdgcn_global_load_lds(
        (const __attribute__((address_space(1))) unsigned int*)g,
        (__attribute__((address_space(3))) unsigned int*)l,
        16, 0, 0);
}

__device__ __forceinline__ void merge_top2(float& v1, int& i1, float& v2, int& i2,
                                           float ov1, int oi1, float ov2, int oi2) {
    bool aw = (v1 > ov1) || (v1 == ov1 && i1 < oi1);
    float w1v = aw ? v1 : ov1;  int w1i = aw ? i1 : oi1;
    float c2v = aw ? v2 : ov2;  int c2i = aw ? i2 : oi2;   // winner's own #2
    float l1v = aw ? ov1 : v1;  int l1i = aw ? oi1 : i1;   // loser's #1
    bool bw = (c2v > l1v) || (c2v == l1v && c2i < l1i);
    v1 = w1v; i1 = w1i;
    v2 = bw ? c2v : l1v; i2 = bw ? c2i : l1i;
}

// packed-key top-2 fold: 3 VALU (min_i32 + 2 max_i32)
__device__ __forceinline__ void kfold(int& t1, int& t2, int key) {
    int m = (key < t1) ? key : t1;
    t2 = (t2 > m) ? t2 : m;
    t1 = (t1 > key) ? t1 : key;
}

// ---------------- prep: normalized patches -> bf16 hi/lo, [65536][384] ----------------
__global__ __launch_bounds__(256) void prep_patches_kernel(
    const float* __restrict__ pixels, unsigned short* __restrict__ Abf)
{
    __shared__ float inv[64];
    const int b = blockIdx.x, t = threadIdx.x;
    const float* pix = pixels + (size_t)b * 3 * 4096;
    if (t < 64) {
        int gr = t >> 3, gc = t & 7;
        const float* pb = pix + gr * 8 * 64 + gc * 8;
        float s = 0.f;
        #pragma unroll
        for (int ch = 0; ch < 3; ++ch)
            #pragma unroll
            for (int r = 0; r < 8; ++r)
                #pragma unroll
                for (int c = 0; c < 8; ++c) {
                    float x = pb[ch * 4096 + r * 64 + c];
                    s += x * x;
                }
        inv[t] = 1.f / fmaxf(sqrtf(s), 1e-8f);
    }
    __syncthreads();
    for (int i = t; i < 64 * 192; i += 256) {
        int p = i / 192, d = i - p * 192;
        int ch = d >> 6, r = (d >> 3) & 7, c = d & 7;
        int gr = p >> 3, gc = p & 7;
        float x = pix[ch * 4096 + (gr * 8 + r) * 64 + gc * 8 + c] * inv[p];
        __hip_bfloat16 h = __float2bfloat16(x);
        float hf = __bfloat162float(h);
        __hip_bfloat16 lo = __float2bfloat16(x - hf);
        size_t row = (size_t)b * 64 + p;
        Abf[row * KP + d]       = *(unsigned short*)&h;
        Abf[row * KP + 192 + d] = *(unsigned short*)&lo;
    }
}

// ---------------- prep: codebook -> bf16 hi/lo, [4096][384] ----------------
__global__ __launch_bounds__(256) void prep_codebook_kernel(
    const float* __restrict__ cb, unsigned short* __restrict__ Bbf)
{
    int i = blockIdx.x * 256 + threadIdx.x;
    if (i >= KCODES * PDIM) return;
    int n = i / PDIM, d = i - n * PDIM;
    float x = cb[i];
    __hip_bfloat16 h = __float2bfloat16(x);
    float hf = __bfloat162float(h);
    __hip_bfloat16 lo = __float2bfloat16(x - hf);
    Bbf[(size_t)n * KP + d]       = *(unsigned short*)&h;
    Bbf[(size_t)n * KP + 192 + d] = *(unsigned short*)&lo;
}

// ---------------- bf16 MFMA GEMM (32x32x16) + fused packed-key top-2 ----------------
// 256x256 block tile, 8 waves (4M x 2N), wave tile 64x128 as 2x4 tiles of 32x32.
// Virtual K=576: A [hi|hi|lo], B [hi|lo|hi] => hi*hi + hi*lo + lo*hi.
// Late-validation schedule: ONE {vmcnt(8); s_barrier} at END of step s
// validates buf[(s+1)&3]; step s+1's ds_reads issue with NO wait.
// 4 LDS buffers, stage distance 3.
__global__ __launch_bounds__(512) void gemm_top2_kernel(
    const unsigned short* __restrict__ A, const unsigned short* __restrict__ B,
    float* __restrict__ o1v, int* __restrict__ o1i,
    float* __restrict__ o2v, int* __restrict__ o2i)
{
    __shared__ unsigned short As[4][8192];   // 4 x 16KB (256 rows x 32 k)
    __shared__ unsigned short Bs[4][8192];   // 4 x 16KB (256 cols x 32 k)

    const int t = threadIdx.x;          // 0..511
    const int w = t >> 6;               // wave 0..7
    const int l = t & 63;
    const int l31 = l & 31, hi5 = l >> 5;
    const int wr = w >> 1, wc = w & 1;  // 4M x 2N wave grid
    const int m0 = blockIdx.x * 256;

    // staging: thread t covers 16B chunk t (rows 0..127) and 512+t (rows 128..255)
    const int srow = t >> 2;                      // 0..127
    const int kc   = (t & 3) ^ ((srow >> 1) & 3); // swizzled k-chunk (involution)
    const unsigned short* a0b = A + (size_t)(m0 + srow) * KP + kc * 8;
    const unsigned short* b0b = B + (size_t)srow * KP + kc * 8;

    // LDS read offsets (ushort units). Fragment mapping for mfma_32x32x16:
    // A row = l&31 (+tile), k = hi5*8 + j within the ksub*16 half.
    int aoff[2][2], boff[2][4];
    #pragma unroll
    for (int ks = 0; ks < 2; ++ks) {
        #pragma unroll
        for (int rt = 0; rt < 2; ++rt) {
            int row = wr * 64 + rt * 32 + l31;
            aoff[ks][rt] = row * 32 + (((ks * 2 + hi5) ^ ((row >> 1) & 3)) * 8);
        }
        #pragma unroll
        for (int cf = 0; cf < 4; ++cf) {
            int col = wc * 128 + cf * 32 + l31;
            boff[ks][cf] = col * 32 + (((ks * 2 + hi5) ^ ((col >> 1) & 3)) * 8);
        }
    }

    int t1k[32], t2k[32];
    #pragma unroll
    for (int e = 0; e < 32; ++e) { t1k[e] = (int)0x80000000; t2k[e] = (int)0x80000000; }

    auto stageA = [&](int sj, int sbuf) {
        int k0 = sj * 32;
        int kA = (k0 < 192) ? k0 : (k0 - 192);   // A: [hi|hi|lo]
        char* Ad = (char*)As[sbuf] + w * 1024;
        const unsigned short* ga = a0b + kA;
        gload_lds16(ga, Ad);
        gload_lds16(ga + 128 * KP, Ad + 8192);
    };
    auto stageB = [&](int sct, int sj, int sbuf) {
        int k0 = sj * 32;
        int kB = (k0 < 384) ? k0 : (k0 - 384);   // B: [hi|lo|hi]
        char* Bd = (char*)Bs[sbuf] + w * 1024;
        const unsigned short* gb = b0b + sct * (256 * KP) + kB;
        gload_lds16(gb, Bd);
        gload_lds16(gb + 128 * KP, Bd + 8192);
    };

    // prologue: stage kt = 0,1,2 into bufs 0,1,2 (12 loads in flight);
    // vmcnt(8) => my stage-0 loads landed; barrier => everyone's.
    stageA(0, 0); stageB(0, 0, 0);
    stageA(1, 1); stageB(0, 1, 1);
    stageA(2, 2); stageB(0, 2, 2);
    asm volatile("s_waitcnt vmcnt(8)\n\ts_barrier" ::: "memory");

    f32x16 acc[2][4];
    int buf = 0;
    int stct = 0, stj = 3;   // stage target = s+3 as (ct, j)

    for (int ct = 0; ct < NCT; ++ct) {
      for (int j = 0; j < NKS; ++j) {
        const unsigned short* Ab = As[buf];
        const unsigned short* Bb = Bs[buf];
        const int sbuf = (buf + 3) & 3;

        // ---------- phase 0 (ksub 0) ----------
        // buf was validated at the END barrier of the previous step.
        bf16x8 a0[2], g0[4];
        #pragma unroll
        for (int rt = 0; rt < 2; ++rt) a0[rt] = *(const bf16x8*)&Ab[aoff[0][rt]];
        #pragma unroll
        for (int cf = 0; cf < 4; ++cf) g0[cf] = *(const bf16x8*)&Bb[boff[0][cf]];
        if (stct < NCT) stageA(stj, sbuf);

        if (j == 0) {
            #pragma unroll
            for (int i = 0; i < 2; ++i)
                #pragma unroll
                for (int jj = 0; jj < 4; ++jj)
                    #pragma unroll
                    for (int r = 0; r < 16; ++r) acc[i][jj][r] = 0.f;
        }

        asm volatile("s_waitcnt lgkmcnt(0)" ::: "memory");
        __builtin_amdgcn_sched_barrier(0);
        __builtin_amdgcn_s_setprio(1);
        #pragma unroll
        for (int rt = 0; rt < 2; ++rt)
            #pragma unroll
            for (int cf = 0; cf < 4; ++cf)
                acc[rt][cf] = __builtin_amdgcn_mfma_f32_32x32x16_bf16(a0[rt], g0[cf], acc[rt][cf], 0, 0, 0);
        __builtin_amdgcn_s_setprio(0);

        // ---------- phase 1 (ksub 1) ----------
        bf16x8 a1[2], g1[4];
        #pragma unroll
        for (int rt = 0; rt < 2; ++rt) a1[rt] = *(const bf16x8*)&Ab[aoff[1][rt]];
        #pragma unroll
        for (int cf = 0; cf < 4; ++cf) g1[cf] = *(const bf16x8*)&Bb[boff[1][cf]];
        if (stct < NCT) stageB(stct, stj, sbuf);

        asm volatile("s_waitcnt lgkmcnt(0)" ::: "memory");
        __builtin_amdgcn_sched_barrier(0);
        __builtin_amdgcn_s_setprio(1);
        #pragma unroll
        for (int rt = 0; rt < 2; ++rt)
            #pragma unroll
            for (int cf = 0; cf < 4; ++cf)
                acc[rt][cf] = __builtin_amdgcn_mfma_f32_32x32x16_bf16(a1[rt], g1[cf], acc[rt][cf], 0, 0, 0);
        __builtin_amdgcn_s_setprio(0);
        __builtin_amdgcn_sched_barrier(0);

        // ---------- end-of-step sync: validate buf[(s+1)&3] ----------
        if (ct < NCT - 1 || j < NKS - 3) {
            asm volatile("s_waitcnt vmcnt(8)\n\ts_barrier" ::: "memory");
        } else if (j == NKS - 3) {
            asm volatile("s_waitcnt vmcnt(4)\n\ts_barrier" ::: "memory");
        } else if (j == NKS - 2) {
            asm volatile("s_waitcnt vmcnt(0)\n\ts_barrier" ::: "memory");
        } // last step: no barrier (epilogue __syncthreads covers)

        // fold after the barrier (pure-register; overlaps next step's ds_reads).
        // 6 low mantissa bits carry (ct,cf); chop <= 8e-6 << 2e-4 fp64 gate.
        if (j == NKS - 1) {
            #pragma unroll
            for (int cf = 0; cf < 4; ++cf) {
                const int inv6 = 0x3F ^ ((ct << 2) | cf);   // wave-uniform
                #pragma unroll
                for (int rt = 0; rt < 2; ++rt)
                    #pragma unroll
                    for (int r = 0; r < 16; ++r) {
                        int key = (__float_as_int(acc[rt][cf][r]) & ~0x3F) | inv6;
                        kfold(t1k[rt * 16 + r], t2k[rt * 16 + r], key);
                    }
            }
        }

        if (stct < NCT && ++stj == NKS) { stj = 0; ++stct; }
        buf = (buf + 1) & 3;
      }
    }

    // ---- decode keys -> (value, index); idx = (ct*4+cf)*... col = l&31 ----
    float p1v[32], p2v[32];
    int   p1i[32], p2i[32];
    #pragma unroll
    for (int e = 0; e < 32; ++e) {
        p1v[e] = __int_as_float(t1k[e] & ~0x3F);
        int e6 = 0x3F ^ (t1k[e] & 0x3F);
        p1i[e] = (e6 >> 2) * 256 + wc * 128 + (e6 & 3) * 32 + l31;
        p2v[e] = __int_as_float(t2k[e] & ~0x3F);
        int e6b = 0x3F ^ (t2k[e] & 0x3F);
        p2i[e] = (e6b >> 2) * 256 + wc * 128 + (e6b & 3) * 32 + l31;
    }

    // butterfly top-2 reduce across the 32 col-lanes (stays within half-wave)
    #pragma unroll
    for (int e = 0; e < 32; ++e) {
        #pragma unroll
        for (int m = 1; m < 32; m <<= 1) {
            float ov1 = __shfl_xor(p1v[e], m);
            int   oi1 = __shfl_xor(p1i[e], m);
            float ov2 = __shfl_xor(p2v[e], m);
            int   oi2 = __shfl_xor(p2i[e], m);
            merge_top2(p1v[e], p1i[e], p2v[e], p2i[e], ov1, oi1, ov2, oi2);
        }
    }

    // cross-wave (column-half) merge via LDS scratch (reuse As; pipeline drained)
    __syncthreads();
    float* r1v = (float*)As;           // [256][2]
    float* r2v = r1v + 512;
    int*   r1i = (int*)(r2v + 512);
    int*   r2i = r1i + 512;
    if (l31 == 0) {   // lanes 0 and 32 of each wave
        #pragma unroll
        for (int rt = 0; rt < 2; ++rt)
            #pragma unroll
            for (int r = 0; r < 16; ++r) {
                const int e = rt * 16 + r;
                // C/D row mapping: (r&3) + 8*(r>>2) + 4*hi5
                int row = wr * 64 + rt * 32 + (r & 3) + 8 * (r >> 2) + 4 * hi5;
                r1v[row * 2 + wc] = p1v[e]; r1i[row * 2 + wc] = p1i[e];
                r2v[row * 2 + wc] = p2v[e]; r2i[row * 2 + wc] = p2i[e];
            }
    }
    __syncthreads();
    if (t < 256) {
        float v1 = r1v[t * 2], v2 = r2v[t * 2];
        int   i1 = r1i[t * 2], i2 = r2i[t * 2];
        merge_top2(v1, i1, v2, i2, r1v[t * 2 + 1], r1i[t * 2 + 1],
                                   r2v[t * 2 + 1], r2i[t * 2 + 1]);
        int grow = m0 + t;
        o1v[grow] = v1; o1i[grow] = i1;
        o2v[grow] = v2; o2i[grow] = i2;
    }
}

// ---------------- fp64 refinement of near-tie argmax ----------------
__global__ __launch_bounds__(256) void refine_kernel(
    const float* __restrict__ pixels, const float* __restrict__ codebook,
    const float* __restrict__ o1v, const int* __restrict__ o1i,
    const float* __restrict__ o2v, const int* __restrict__ o2i,
    int* __restrict__ idx_out, float* __restrict__ idxf_out)
{
    int row = blockIdx.x * 256 + threadIdx.x;
    if (row >= MROWS) return;
    float v1 = o1v[row], v2 = o2v[row];
    int   i1 = o1i[row], i2 = o2i[row];
    int idx = i1;
    if (v1 - v2 <= 2e-4f) {
        int b = row >> 6, p = row & 63;
        int gr = p >> 3, gc = p & 7;
        const float* pb = pixels + (size_t)b * 3 * 4096 + gr * 8 * 64 + gc * 8;
        const float* c1 = codebook + (size_t)i1 * PDIM;
        const float* c2 = codebook + (size_t)i2 * PDIM;
        double s1 = 0.0, s2 = 0.0;
        for (int d = 0; d < PDIM; ++d) {
            int ch = d >> 6, r = (d >> 3) & 7, c = d & 7;
            double x = (double)pb[ch * 4096 + r * 64 + c];
            s1 += x * (double)c1[d];
            s2 += x * (double)c2[d];
        }
        if (s2 > s1 || (s2 == s1 && i2 < i1)) idx = i2;
    }
    idx_out[row] = idx;
    idxf_out[row] = (float)idx;
}

// ---------------- fused z_real / z_local / z_vsa ----------------
__global__ __launch_bounds__(256) void zv_kernel(
    const float* __restrict__ emb, const float* __restrict__ vsa,
    const float* __restrict__ roles, const int* __restrict__ idx,
    float* __restrict__ z_real, float* __restrict__ z_local,
    float* __restrict__ z_vsa)
{
    __shared__ int sidx[64];
    int b = blockIdx.x, t = threadIdx.x;
    if (t < 64) sidx[t] = idx[b * 64 + t];
    __syncthreads();
    float s[8], sl[8];
    #pragma unroll
    for (int j = 0; j < 8; ++j) { s[j] = 0.f; sl[j] = 0.f; }
    for (int p = 0; p < 64; ++p) {
        int gr = p >> 3, gc = p & 7;
        bool ag = (gr >= 3 && gr < 6 && gc >= 3 && gc < 6);
        const float* er = emb + (size_t)sidx[p] * EDIM + t * 8;
        float v[8];
        *(float4*)&v[0] = *(const float4*)er;
        *(float4*)&v[4] = *(const float4*)(er + 4);
        #pragma unroll
        for (int j = 0; j < 8; ++j) s[j] += v[j];
        if (ag) {
            #pragma unroll
            for (int j = 0; j < 8; ++j) sl[j] += v[j];
        }
    }
    float* zr = z_real + (size_t)b * EDIM + t * 8;
    float* zl = z_local + (size_t)b * EDIM + t * 8;
    #pragma unroll
    for (int j = 0; j < 8; ++j) {
        zr[j] = s[j] * (1.f / 64.f);
        zl[j] = sl[j] * (1.f / 9.f);
    }

    // z_vsa over the 16 central patches
    float cnt[8];
    #pragma unroll
    for (int j = 0; j < 8; ++j) cnt[j] = 0.f;
    for (int cp = 0; cp < 16; ++cp) {
        int p = (2 + (cp >> 2)) * 8 + 2 + (cp & 3);
        const float* vr = vsa + (size_t)sidx[p] * VDIM + t * 8;
        const float* pr = roles + (size_t)p * VDIM + t * 8;
        float a[8], r[8];
        *(float4*)&a[0] = *(const float4*)vr;
        *(float4*)&a[4] = *(const float4*)(vr + 4);
        *(float4*)&r[0] = *(const float4*)pr;
        *(float4*)&r[4] = *(const float4*)(pr + 4);
        #pragma unroll
        for (int j = 0; j < 8; ++j) cnt[j] += (a[j] != r[j]) ? 1.f : 0.f;
    }
    #pragma unroll
    for (int j = 0; j < 8; ++j)
        z_vsa[(size_t)b * VDIM + t * 8 + j] = cnt[j] > 8.f ? 1.f : 0.f;
}

extern "C" void kernel_launch(void* const* d_in, const int* in_sizes, int n_in,
                              void* d_out, int out_size, void* d_ws, size_t ws_size,
                              hipStream_t stream) {
    const float* pixels         = (const float*)d_in[0];
    const float* codebook       = (const float*)d_in[1];
    const float* embeddings     = (const float*)d_in[2];
    const float* codebook_vsa   = (const float*)d_in[3];
    const float* position_roles = (const float*)d_in[4];

    float* out     = (float*)d_out;
    float* z_real  = out;                 // 1024*2048
    float* z_vsa   = out + 2097152;       // 1024*2048
    float* idxf    = out + 4194304;       // 1024*64
    float* z_local = out + 4259840;       // 1024*2048

    char* ws = (char*)d_ws;
    unsigned short* Abf = (unsigned short*)(ws);                     // 50331648 B
    unsigned short* Bbf = (unsigned short*)(ws + 50331648);          //  3145728 B
    float* o1v = (float*)(ws + 53477376);
    int*   o1i = (int*)  (ws + 54001664);
    float* o2v = (float*)(ws + 54525952);
    int*   o2i = (int*)  (ws + 55050240);
    int*   idxws = (int*)(ws + 55574528);

    prep_patches_kernel<<<NIMG, 256, 0, stream>>>(pixels, Abf);
    prep_codebook_kernel<<<(KCODES * PDIM + 255) / 256, 256, 0, stream>>>(codebook, Bbf);

    gemm_top2_kernel<<<MROWS / 256, 512, 0, stream>>>(Abf, Bbf, o1v, o1i, o2v, o2i);

    refine_kernel<<<MROWS / 256, 256, 0, stream>>>(pixels, codebook,
        o1v, o1i, o2v, o2i, idxws, idxf);
    zv_kernel<<<NIMG, 256, 0, stream>>>(embeddings, codebook_vsa, position_roles,
        idxws, z_real, z_local, z_vsa);
}

// Round 10
// 208.865 us; speedup vs baseline: 1.9869x; 1.9869x over previous
//
#include <hip/hip_runtime.h>
#include <hip/hip_bf16.h>
#include <math.h>

#define NIMG 1024
#define NPATCH 64
#define PDIM 192
#define KCODES 4096
#define EDIM 2048
#define VDIM 2048
#define MROWS (NIMG * NPATCH)   // 65536
#define KP 192                  // fp16 single-term: K = 192
#define NKS 6                   // K-steps (BK=32) per column tile
#define NCT 16                  // column tiles of 256 codes

typedef _Float16 f16x8 __attribute__((ext_vector_type(8)));
typedef __attribute__((ext_vector_type(4))) float f32x4;

__device__ __forceinline__ void gload_lds16(const void* g, void* l) {
    __builtin_amdgcn_global_load_lds(
        (const __attribute__((address_space(1))) unsigned int*)g,
        (__attribute__((address_space(3))) unsigned int*)l,
        16, 0, 0);
}

__device__ __forceinline__ void merge_top2(float& v1, int& i1, float& v2, int& i2,
                                           float ov1, int oi1, float ov2, int oi2) {
    bool aw = (v1 > ov1) || (v1 == ov1 && i1 < oi1);
    float w1v = aw ? v1 : ov1;  int w1i = aw ? i1 : oi1;
    float c2v = aw ? v2 : ov2;  int c2i = aw ? i2 : oi2;   // winner's own #2
    float l1v = aw ? ov1 : v1;  int l1i = aw ? oi1 : i1;   // loser's #1
    bool bw = (c2v > l1v) || (c2v == l1v && c2i < l1i);
    v1 = w1v; i1 = w1i;
    v2 = bw ? c2v : l1v; i2 = bw ? c2i : l1i;
}

// packed-key top-2 fold: 3 VALU (min_i32 + 2 max_i32)
__device__ __forceinline__ void kfold(int& t1, int& t2, int key) {
    int m = (key < t1) ? key : t1;
    t2 = (t2 > m) ? t2 : m;
    t1 = (t1 > key) ? t1 : key;
}

// ---------------- prep: normalized patches -> fp16, [65536][192] ----------------
__global__ __launch_bounds__(256) void prep_patches_kernel(
    const float* __restrict__ pixels, unsigned short* __restrict__ Ah)
{
    __shared__ float inv[64];
    const int b = blockIdx.x, t = threadIdx.x;
    const float* pix = pixels + (size_t)b * 3 * 4096;
    if (t < 64) {
        int gr = t >> 3, gc = t & 7;
        const float* pb = pix + gr * 8 * 64 + gc * 8;
        float s = 0.f;
        #pragma unroll
        for (int ch = 0; ch < 3; ++ch)
            #pragma unroll
            for (int r = 0; r < 8; ++r)
                #pragma unroll
                for (int c = 0; c < 8; ++c) {
                    float x = pb[ch * 4096 + r * 64 + c];
                    s += x * x;
                }
        inv[t] = 1.f / fmaxf(sqrtf(s), 1e-8f);
    }
    __syncthreads();
    for (int i = t; i < 64 * 192; i += 256) {
        int p = i / 192, d = i - p * 192;
        int ch = d >> 6, r = (d >> 3) & 7, c = d & 7;
        int gr = p >> 3, gc = p & 7;
        float x = pix[ch * 4096 + (gr * 8 + r) * 64 + gc * 8 + c] * inv[p];
        _Float16 h = (_Float16)x;
        Ah[((size_t)b * 64 + p) * KP + d] = *(unsigned short*)&h;
    }
}

// ---------------- prep: codebook -> fp16, [4096][192] ----------------
__global__ __launch_bounds__(256) void prep_codebook_kernel(
    const float* __restrict__ cb, unsigned short* __restrict__ Bh)
{
    int i = blockIdx.x * 256 + threadIdx.x;
    if (i >= KCODES * PDIM) return;
    _Float16 h = (_Float16)cb[i];
    Bh[i] = *(unsigned short*)&h;
}

// ---------------- fp16 MFMA GEMM (16x16x32, K=192) + fused packed-key top-2 ----
// 256x256 block tile, 8 waves (4M x 2N), wave tile 64x128, BK=32.
// A panel (256 x 192 fp16 = 96 KB) staged ONCE, resident across all 16 column
// tiles. B: 3-buffer ring (48 KB), stage distance 2, counted vmcnt(2) at the
// single end-of-step barrier (validates next B buffer; no drain in main loop).
__global__ __launch_bounds__(512) void gemm_top2_kernel(
    const unsigned short* __restrict__ A, const unsigned short* __restrict__ B,
    float* __restrict__ o1v, int* __restrict__ o1i,
    float* __restrict__ o2v, int* __restrict__ o2i)
{
    __shared__ unsigned short Asl[6][8192];   // 96 KB: A panel, tile j = K [32j,32j+32)
    __shared__ unsigned short Bsl[3][8192];   // 48 KB: B ring

    const int t = threadIdx.x;          // 0..511
    const int w = t >> 6;               // wave 0..7
    const int l = t & 63;
    const int lo4 = l & 15, hi4 = l >> 4;
    const int wr = w >> 1, wc = w & 1;  // 4M x 2N wave grid
    const int m0 = blockIdx.x * 256;

    // staging: thread t covers 16B chunk t (rows 0..127) and 512+t (rows 128..255)
    const int srow = t >> 2;                      // 0..127
    const int kc   = (t & 3) ^ ((srow >> 1) & 3); // swizzled k-chunk (involution)
    const unsigned short* a0b = A + (size_t)(m0 + srow) * KP + kc * 8;
    const unsigned short* b0b = B + (size_t)srow * KP + kc * 8;

    // LDS read offsets (ushort units within one 8192-ushort tile)
    int aoff[4], boff[8];
    #pragma unroll
    for (int rt = 0; rt < 4; ++rt) {
        int row = wr * 64 + rt * 16 + lo4;
        aoff[rt] = row * 32 + (hi4 ^ ((row >> 1) & 3)) * 8;
    }
    #pragma unroll
    for (int cf = 0; cf < 8; ++cf) {
        int col = wc * 128 + cf * 16 + lo4;
        boff[cf] = col * 32 + (hi4 ^ ((col >> 1) & 3)) * 8;
    }

    int t1k[16], t2k[16];
    #pragma unroll
    for (int e = 0; e < 16; ++e) { t1k[e] = (int)0x80000000; t2k[e] = (int)0x80000000; }

    auto stageA = [&](int j) {
        char* Ad = (char*)Asl[j] + w * 1024;
        const unsigned short* ga = a0b + j * 32;
        gload_lds16(ga, Ad);
        gload_lds16(ga + 128 * KP, Ad + 8192);
    };
    auto stageB = [&](int sct, int sj, int sbuf) {
        char* Bd = (char*)Bsl[sbuf] + w * 1024;
        const unsigned short* gb = b0b + sct * (256 * KP) + sj * 32;
        gload_lds16(gb, Bd);
        gload_lds16(gb + 128 * KP, Bd + 8192);
    };

    // prologue: full A panel (12 loads) + B steps 0,1 (4 loads).
    // vmcnt(2): A + B0 landed (B1's 2 loads may remain in flight); barrier.
    #pragma unroll
    for (int j = 0; j < 6; ++j) stageA(j);
    stageB(0, 0, 0);
    stageB(0, 1, 1);
    asm volatile("s_waitcnt vmcnt(2)\n\ts_barrier" ::: "memory");

    f32x4 acc[4][8];
    int bb = 0, sb = 2;      // current B buffer (s%3), stage buffer ((s+2)%3)
    int stct = 0, stj = 2;   // stage target = s+2 as (ct, j)

    for (int ct = 0; ct < NCT; ++ct) {
      for (int j = 0; j < NKS; ++j) {
        const unsigned short* Ab = Asl[j];
        const unsigned short* Bb = Bsl[bb];

        // ---------- phase 0 ----------
        // Bb was validated at the END barrier of the previous step.
        f16x8 af[4], bg[4];
        #pragma unroll
        for (int rt = 0; rt < 4; ++rt) af[rt] = *(const f16x8*)&Ab[aoff[rt]];
        #pragma unroll
        for (int cf = 0; cf < 4; ++cf) bg[cf] = *(const f16x8*)&Bb[boff[cf]];
        // stage(s+2) overwrites the ring slot read at step s-1; all waves
        // passed the s-1 end-barrier after finishing those reads => safe.
        if (stct < NCT) stageB(stct, stj, sb);

        if (j == 0) {
            #pragma unroll
            for (int i = 0; i < 4; ++i)
                #pragma unroll
                for (int jj = 0; jj < 8; ++jj) acc[i][jj] = (f32x4){0.f, 0.f, 0.f, 0.f};
        }

        asm volatile("s_waitcnt lgkmcnt(0)" ::: "memory");
        __builtin_amdgcn_sched_barrier(0);
        __builtin_amdgcn_s_setprio(1);
        #pragma unroll
        for (int rt = 0; rt < 4; ++rt)
            #pragma unroll
            for (int cf = 0; cf < 4; ++cf)
                acc[rt][cf] = __builtin_amdgcn_mfma_f32_16x16x32_f16(af[rt], bg[cf], acc[rt][cf], 0, 0, 0);
        __builtin_amdgcn_s_setprio(0);

        // ---------- phase 1 ----------
        f16x8 bh[4];
        #pragma unroll
        for (int cf = 0; cf < 4; ++cf) bh[cf] = *(const f16x8*)&Bb[boff[cf + 4]];

        asm volatile("s_waitcnt lgkmcnt(0)" ::: "memory");
        __builtin_amdgcn_sched_barrier(0);
        __builtin_amdgcn_s_setprio(1);
        #pragma unroll
        for (int rt = 0; rt < 4; ++rt)
            #pragma unroll
            for (int cf = 0; cf < 4; ++cf)
                acc[rt][cf + 4] = __builtin_amdgcn_mfma_f32_16x16x32_f16(af[rt], bh[cf], acc[rt][cf + 4], 0, 0, 0);
        __builtin_amdgcn_s_setprio(0);
        __builtin_amdgcn_sched_barrier(0);

        // ---------- end-of-step sync: validate B ring slot for s+1 ----------
        // outstanding stages here: {s+1, s+2} (2 loads each, clipped at end).
        if (ct < NCT - 1 || j < NKS - 2) {
            asm volatile("s_waitcnt vmcnt(2)\n\ts_barrier" ::: "memory");
        } else if (j == NKS - 2) {
            asm volatile("s_waitcnt vmcnt(0)\n\ts_barrier" ::: "memory");
        } // last step: no barrier (epilogue __syncthreads covers)

        // fold after the barrier (pure-register; overlaps next step's ds_reads).
        // 7 low mantissa bits carry (ct,cf); chop ~4e-6 << 4e-4 fp64 gate.
        if (j == NKS - 1) {
            #pragma unroll
            for (int cf = 0; cf < 8; ++cf) {
                const int inv7 = 0x7F ^ ((ct << 3) | cf);   // wave-uniform
                #pragma unroll
                for (int rt = 0; rt < 4; ++rt)
                    #pragma unroll
                    for (int r = 0; r < 4; ++r) {
                        int key = (__float_as_int(acc[rt][cf][r]) & ~0x7F) | inv7;
                        kfold(t1k[rt * 4 + r], t2k[rt * 4 + r], key);
                    }
            }
        }

        if (stct < NCT && ++stj == NKS) { stj = 0; ++stct; }
        if (++bb == 3) bb = 0;
        if (++sb == 3) sb = 0;
      }
    }

    // ---- decode keys -> (value, index) ----
    float p1v[16], p2v[16];
    int   p1i[16], p2i[16];
    #pragma unroll
    for (int e = 0; e < 16; ++e) {
        p1v[e] = __int_as_float(t1k[e] & ~0x7F);
        int lo7 = 0x7F ^ (t1k[e] & 0x7F);
        p1i[e] = ((lo7 >> 3) << 8) + wc * 128 + ((lo7 & 7) << 4) + lo4;
        p2v[e] = __int_as_float(t2k[e] & ~0x7F);
        int lo7b = 0x7F ^ (t2k[e] & 0x7F);
        p2i[e] = ((lo7b >> 3) << 8) + wc * 128 + ((lo7b & 7) << 4) + lo4;
    }

    // intra-wave butterfly top-2 reduce across the 16 col-lanes of each frag row
    #pragma unroll
    for (int e = 0; e < 16; ++e) {
        #pragma unroll
        for (int m = 1; m < 16; m <<= 1) {
            float ov1 = __shfl_xor(p1v[e], m);
            int   oi1 = __shfl_xor(p1i[e], m);
            float ov2 = __shfl_xor(p2v[e], m);
            int   oi2 = __shfl_xor(p2i[e], m);
            merge_top2(p1v[e], p1i[e], p2v[e], p2i[e], ov1, oi1, ov2, oi2);
        }
    }

    // cross-wave (column-half) merge via LDS scratch (reuse Asl; pipeline drained)
    __syncthreads();
    float* r1v = (float*)Asl;          // [256][2]
    float* r2v = r1v + 512;
    int*   r1i = (int*)(r2v + 512);
    int*   r2i = r1i + 512;
    if (lo4 == 0) {
        #pragma unroll
        for (int rt = 0; rt < 4; ++rt)
            #pragma unroll
            for (int r = 0; r < 4; ++r) {
                const int e = rt * 4 + r;
                int row = wr * 64 + rt * 16 + hi4 * 4 + r;   // 0..255
                r1v[row * 2 + wc] = p1v[e]; r1i[row * 2 + wc] = p1i[e];
                r2v[row * 2 + wc] = p2v[e]; r2i[row * 2 + wc] = p2i[e];
            }
    }
    __syncthreads();
    if (t < 256) {
        float v1 = r1v[t * 2], v2 = r2v[t * 2];
        int   i1 = r1i[t * 2], i2 = r2i[t * 2];
        merge_top2(v1, i1, v2, i2, r1v[t * 2 + 1], r1i[t * 2 + 1],
                                   r2v[t * 2 + 1], r2i[t * 2 + 1]);
        int grow = m0 + t;
        o1v[grow] = v1; o1i[grow] = i1;
        o2v[grow] = v2; o2i[grow] = i2;
    }
}

// ---------------- fp64 refinement of near-tie argmax ----------------
__global__ __launch_bounds__(256) void refine_kernel(
    const float* __restrict__ pixels, const float* __restrict__ codebook,
    const float* __restrict__ o1v, const int* __restrict__ o1i,
    const float* __restrict__ o2v, const int* __restrict__ o2i,
    int* __restrict__ idx_out, float* __restrict__ idxf_out)
{
    int row = blockIdx.x * 256 + threadIdx.x;
    if (row >= MROWS) return;
    float v1 = o1v[row], v2 = o2v[row];
    int   i1 = o1i[row], i2 = o2i[row];
    int idx = i1;
    if (v1 - v2 <= 4e-4f) {   // 20-sigma of the fp16 single-term sim error
        int b = row >> 6, p = row & 63;
        int gr = p >> 3, gc = p & 7;
        const float* pb = pixels + (size_t)b * 3 * 4096 + gr * 8 * 64 + gc * 8;
        const float* c1 = codebook + (size_t)i1 * PDIM;
        const float* c2 = codebook + (size_t)i2 * PDIM;
        double s1 = 0.0, s2 = 0.0;
        for (int d = 0; d < PDIM; ++d) {
            int ch = d >> 6, r = (d >> 3) & 7, c = d & 7;
            double x = (double)pb[ch * 4096 + r * 64 + c];
            s1 += x * (double)c1[d];
            s2 += x * (double)c2[d];
        }
        if (s2 > s1 || (s2 == s1 && i2 < i1)) idx = i2;
    }
    idx_out[row] = idx;
    idxf_out[row] = (float)idx;
}

// ---------------- fused z_real / z_local / z_vsa ----------------
__global__ __launch_bounds__(256) void zv_kernel(
    const float* __restrict__ emb, const float* __restrict__ vsa,
    const float* __restrict__ roles, const int* __restrict__ idx,
    float* __restrict__ z_real, float* __restrict__ z_local,
    float* __restrict__ z_vsa)
{
    __shared__ int sidx[64];
    int b = blockIdx.x, t = threadIdx.x;
    if (t < 64) sidx[t] = idx[b * 64 + t];
    __syncthreads();
    float s[8], sl[8];
    #pragma unroll
    for (int j = 0; j < 8; ++j) { s[j] = 0.f; sl[j] = 0.f; }
    for (int p = 0; p < 64; ++p) {
        int gr = p >> 3, gc = p & 7;
        bool ag = (gr >= 3 && gr < 6 && gc >= 3 && gc < 6);
        const float* er = emb + (size_t)sidx[p] * EDIM + t * 8;
        float v[8];
        *(float4*)&v[0] = *(const float4*)er;
        *(float4*)&v[4] = *(const float4*)(er + 4);
        #pragma unroll
        for (int j = 0; j < 8; ++j) s[j] += v[j];
        if (ag) {
            #pragma unroll
            for (int j = 0; j < 8; ++j) sl[j] += v[j];
        }
    }
    float* zr = z_real + (size_t)b * EDIM + t * 8;
    float* zl = z_local + (size_t)b * EDIM + t * 8;
    #pragma unroll
    for (int j = 0; j < 8; ++j) {
        zr[j] = s[j] * (1.f / 64.f);
        zl[j] = sl[j] * (1.f / 9.f);
    }

    // z_vsa over the 16 central patches
    float cnt[8];
    #pragma unroll
    for (int j = 0; j < 8; ++j) cnt[j] = 0.f;
    for (int cp = 0; cp < 16; ++cp) {
        int p = (2 + (cp >> 2)) * 8 + 2 + (cp & 3);
        const float* vr = vsa + (size_t)sidx[p] * VDIM + t * 8;
        const float* pr = roles + (size_t)p * VDIM + t * 8;
        float a[8], r[8];
        *(float4*)&a[0] = *(const float4*)vr;
        *(float4*)&a[4] = *(const float4*)(vr + 4);
        *(float4*)&r[0] = *(const float4*)pr;
        *(float4*)&r[4] = *(const float4*)(pr + 4);
        #pragma unroll
        for (int j = 0; j < 8; ++j) cnt[j] += (a[j] != r[j]) ? 1.f : 0.f;
    }
    #pragma unroll
    for (int j = 0; j < 8; ++j)
        z_vsa[(size_t)b * VDIM + t * 8 + j] = cnt[j] > 8.f ? 1.f : 0.f;
}

extern "C" void kernel_launch(void* const* d_in, const int* in_sizes, int n_in,
                              void* d_out, int out_size, void* d_ws, size_t ws_size,
                              hipStream_t stream) {
    const float* pixels         = (const float*)d_in[0];
    const float* codebook       = (const float*)d_in[1];
    const float* embeddings     = (const float*)d_in[2];
    const float* codebook_vsa   = (const float*)d_in[3];
    const float* position_roles = (const float*)d_in[4];

    float* out     = (float*)d_out;
    float* z_real  = out;                 // 1024*2048
    float* z_vsa   = out + 2097152;       // 1024*2048
    float* idxf    = out + 4194304;       // 1024*64
    float* z_local = out + 4259840;       // 1024*2048

    char* ws = (char*)d_ws;
    unsigned short* Ah = (unsigned short*)(ws);                      // 25165824 B
    unsigned short* Bh = (unsigned short*)(ws + 25165824);           //  1572864 B
    float* o1v = (float*)(ws + 26738688);
    int*   o1i = (int*)  (ws + 27000832);
    float* o2v = (float*)(ws + 27262976);
    int*   o2i = (int*)  (ws + 27525120);
    int*   idxws = (int*)(ws + 27787264);

    prep_patches_kernel<<<NIMG, 256, 0, stream>>>(pixels, Ah);
    prep_codebook_kernel<<<(KCODES * PDIM + 255) / 256, 256, 0, stream>>>(codebook, Bh);

    gemm_top2_kernel<<<MROWS / 256, 512, 0, stream>>>(Ah, Bh, o1v, o1i, o2v, o2i);

    refine_kernel<<<MROWS / 256, 256, 0, stream>>>(pixels, codebook,
        o1v, o1i, o2v, o2i, idxws, idxf);
    zv_kernel<<<NIMG, 256, 0, stream>>>(embeddings, codebook_vsa, position_roles,
        idxws, z_real, z_local, z_vsa);
}